// Round 13
// baseline (25.614 us; speedup 1.0000x reference)
//
#include <hip/hip_runtime.h>
#include <stdint.h>

#define NR 5000
#define NRM1 4999
#define W 640
#define NBLK 2500          // block b: rows b and 4998-b == virtual space of 5000 elems
#define NG 5               // float4 groups per thread: 5*4*256 = 5120 >= 5000
#define PCOUNT 12497500.0f
#define LOG2E 1.44269504088896340736f
#define LN2   0.69314718055994530942f

typedef float f32x2  __attribute__((ext_vector_type(2)));
typedef float float4u __attribute__((ext_vector_type(4)));
struct __attribute__((packed, aligned(4))) f4wrap { float4u v; };
__device__ __forceinline__ float4u load4u(const float* p) {
    return ((const f4wrap*)p)->v;    // 4B-aligned vector load
}

// ---------------- Kernel 1: gather z = x[rows, cols] (once) ----------------
__global__ void gather_z(const float* __restrict__ x,
                         const int* __restrict__ centers,
                         float* __restrict__ z) {
    int t = blockIdx.x * blockDim.x + threadIdx.x;
    if (t < NR) {
        const int2 rc = ((const int2*)centers)[t];
        z[t] = x[rc.x * W + rc.y];
    }
}

// Loss per element, log2 domain (ln2 applied in final_reduce), branchless:
//   s = zj - zr; sl = s*log2e; q = s*sl (= d^2/ln2); lg = log2(1+2^(g*sl))
//   g in {-1,0,1} -> m = g*g in {0,1};  l = q + m*(lg - q)
__global__ __launch_bounds__(256) void pair_loss(const float* __restrict__ gt,
                                                 const float* __restrict__ z,
                                                 float* __restrict__ partials) {
    __shared__ float sz[NR];        // 20000 B -> 8 blocks/CU
    __shared__ float wsum[4];
    const int tid = threadIdx.x;
    const int b = blockIdx.x;

    const float4* __restrict__ zf4 = (const float4*)z;
    for (int t = tid; t < NR / 4; t += 256)
        *(float4*)&sz[4 * t] = zf4[t];
    __syncthreads();

    const int r1 = b, r2 = NR - 2 - b;
    const int len1 = NRM1 - r1;                         // 4999-b
    const int off1 = r1 * NRM1 - (r1 * (r1 - 1)) / 2;   // fits i32
    const int off2 = r2 * NRM1 - (r2 * (r2 - 1)) / 2;
    const int off2v = off2 - len1;
    const int vmax = (r2 > r1) ? 5000 : len1;           // multiples of 4
    const float zr1 = sz[r1], zr2 = sz[r2];

    // ---- batch-issue NG float4 gt loads (independent, fully unrolled) ----
    float4u g4[NG];
    int cb[NG];
    #pragma unroll
    for (int k = 0; k < NG; ++k) {
        const int vb = 4 * tid + 1024 * k;
        const int c = min(vb, vmax - 4);                // clamp: vb<vmax <=> c==vb
        cb[k] = c;
        const float* base = (c < len1) ? (gt + off1) : (gt + off2v);
        g4[k] = load4u(base + c);
    }

    f32x2 acc0 = {0.0f, 0.0f}, acc1 = {0.0f, 0.0f};
    float accS = 0.0f;                                  // straddle fallback acc

    #pragma unroll
    for (int k = 0; k < NG; ++k) {
        const int c = cb[k];
        const int vb = 4 * tid + 1024 * k;
        const bool in1 = c < len1;
        const bool straddle = in1 && (c + 3 >= len1);
        if (!straddle) {
            const float zr = in1 ? zr1 : zr2;
            const int ib = c + (in1 ? r1 + 1 : 0);
            const f32x2 zj0 = { sz[ib],     sz[ib + 1] };
            const f32x2 zj1 = { sz[ib + 2], sz[ib + 3] };
            const f32x2 gg0 = { g4[k].x, g4[k].y };
            const f32x2 gg1 = { g4[k].z, g4[k].w };
            const f32x2 s0 = zj0 - zr,  s1 = zj1 - zr;
            const f32x2 sl0 = s0 * LOG2E, sl1 = s1 * LOG2E;
            const f32x2 t0 = gg0 * sl0, t1 = gg1 * sl1;
            const f32x2 e0 = { exp2f(t0.x), exp2f(t0.y) };
            const f32x2 e1 = { exp2f(t1.x), exp2f(t1.y) };
            const f32x2 p0 = e0 + 1.0f, p1 = e1 + 1.0f;
            const f32x2 lg0 = { __log2f(p0.x), __log2f(p0.y) };
            const f32x2 lg1 = { __log2f(p1.x), __log2f(p1.y) };
            const f32x2 q0 = s0 * sl0, q1 = s1 * sl1;
            const f32x2 m0 = gg0 * gg0, m1 = gg1 * gg1;
            const f32x2 l0 = q0 + m0 * (lg0 - q0);
            const f32x2 l1 = q1 + m1 * (lg1 - q1);
            const float w = (vb < vmax) ? 1.0f : 0.0f;  // group-uniform validity
            acc0 += l0 * w;
            acc1 += l1 * w;
        } else if (vb < vmax) {
            // rare: one group per block spans the row1/row2 junction.
            // reload g from the correct base per element; full scalar loss.
            #pragma unroll
            for (int e = 0; e < 4; ++e) {
                const int ce = c + e;
                const bool i1 = ce < len1;
                const float zj = sz[ce + (i1 ? r1 + 1 : 0)];
                const float zr = i1 ? zr1 : zr2;
                const float g = gt[(i1 ? off1 : off2v) + ce];
                const float s  = zj - zr;
                const float sl = s * LOG2E;
                const float lg = __log2f(1.0f + exp2f(g * sl));
                accS += (g != 0.0f) ? lg : s * sl;
            }
        }
    }

    const f32x2 accp = acc0 + acc1;
    float acc = accp.x + accp.y + accS;

    // deterministic block reduction: wave shuffle tree + LDS across 4 waves
    for (int o = 32; o > 0; o >>= 1) acc += __shfl_down(acc, o, 64);
    if ((tid & 63) == 0) wsum[tid >> 6] = acc;
    __syncthreads();
    if (tid == 0)
        partials[b] = (wsum[0] + wsum[1]) + (wsum[2] + wsum[3]);
}

// ---------------- Kernel 3: deterministic final reduce (applies ln2/P) ----------------
__global__ __launch_bounds__(256) void final_reduce(const float* __restrict__ partials,
                                                    float* __restrict__ out) {
    __shared__ float wsum[4];
    float acc = 0.0f;
    const float4* __restrict__ p4 = (const float4*)partials;   // 2500 = 625 float4s
    for (int t = threadIdx.x; t < NBLK / 4; t += 256) {
        const float4 v = p4[t];
        acc += (v.x + v.y) + (v.z + v.w);
    }
    for (int o = 32; o > 0; o >>= 1) acc += __shfl_down(acc, o, 64);
    if ((threadIdx.x & 63) == 0) wsum[threadIdx.x >> 6] = acc;
    __syncthreads();
    if (threadIdx.x == 0)
        out[0] = ((wsum[0] + wsum[1]) + (wsum[2] + wsum[3])) * (LN2 / PCOUNT);
}

extern "C" void kernel_launch(void* const* d_in, const int* in_sizes, int n_in,
                              void* d_out, int out_size, void* d_ws, size_t ws_size,
                              hipStream_t stream) {
    const float* x       = (const float*)d_in[0];   // (480,640) f32
    const float* gt      = (const float*)d_in[1];   // (P,) f32
    const int*   centers = (const int*)d_in[2];     // (5000,2) int32
    float* out = (float*)d_out;                     // scalar f32

    float* z        = (float*)d_ws;                 // NR floats (16B-aligned)
    float* partials = z + NR;                       // NBLK floats

    gather_z<<<(NR + 255) / 256, 256, 0, stream>>>(x, centers, z);
    pair_loss<<<NBLK, 256, 0, stream>>>(gt, z, partials);
    final_reduce<<<1, 256, 0, stream>>>(partials, out);
}